// Round 16
// baseline (18.348 us; speedup 1.0000x reference)
//
#include <hip/hip_runtime.h>

// SigmoidLoss: out = sum_n mean_{s,t} [ softplus(z) - W[s,t]*z ],  z = f1[n,s]*f2[n,t]
// f1[n,s] = emb[bi, s, ei], f2[n,s] = emb[32+bi, s, ei],  n = bi*64 + ei
// W banded: W[s,t] = 1-0.05q, q = (t>=s ? t-s : s-t-1), zero for q >= 20.
//
// G-table: G_e(c) = sum_s softplus(f1[s]*c) at 16 nodes on [-6,6]; 4-point
// cubic Lagrange eval (absmax 0.0 across R11-R13). W-term via per-ei prefix
// sums P0 = sum f2, P1 = sum t*f2 (closed-form band).
//
// R16: fused kernel + DETERMINISTIC TICKET RESET. R14/R15 failed because the
// mod-window winner rule is only "last arrival" when ticket starts == 0 mod
// 256 (poison 0xAA.. made the 86th arrival the winner -> stale reads). Fix:
// hipMemsetAsync(ticket, 0, 4, stream) before the kernel (graph-legal memset
// node, re-run every replay). Publish order per block: atomicExch(partial) ->
// s_waitcnt vmcnt(0) ("memory") -> atomicAdd(ticket). Winner (ticket==255)
// therefore sees ALL exchanges complete; reads via device-scope atomics.

#define SIDE 256
#define NB 32
#define NE 64
#define NBLK 256          // 32 bi x 8 ei-groups (8 ei each)
#define LOG2E 1.4426950408889634f
#define LN2 0.6931471805599453f
#define NODES 16
#define CRANGE 6.0f
#define HSTEP (12.0f / 15.0f)
#define USCALE (15.0f / 12.0f)

__global__ __launch_bounds__(1024) void sigloss_fused(const float* __restrict__ emb,
                                                      float* __restrict__ partial,
                                                      unsigned int* __restrict__ ticket,
                                                      float* __restrict__ out) {
    const int bid  = blockIdx.x;
    const int g    = (bid >> 3) + ((bid & 7) << 5);  // XCD swizzle (bijective on 256)
    const int bi   = g >> 3;
    const int ei0  = (g & 7) << 3;
    const int tid  = threadIdx.x;   // 0..1023
    const int wv   = tid >> 6;      // wave 0..15
    const int lane = tid & 63;

    __shared__ __align__(16) float f1p[8][8 * 36];
    __shared__ float f2s[8][SIDE + 4];
    __shared__ float P0[8][SIDE + 1];
    __shared__ float P1[8][SIDE + 1];
    __shared__ float table[8][NODES + 2];
    __shared__ float wsum[16];
    __shared__ unsigned int s_tk;

    // ---- staging: two float4 per s-row (8 ei), paired lanes share a line ----
    {
        const int half = tid >> 9;          // 0: f1, 1: f2
        const int s    = (tid >> 1) & 255;
        const int h    = tid & 1;           // which float4 (4 ei)
        const float4 v = *(const float4*)(emb
            + (size_t)(half ? NB + bi : bi) * (SIDE * NE) + (size_t)s * NE + ei0 + 4 * h);
        const int e0 = 4 * h;
        if (half == 0) {
            const int idx = ((s >> 5) * 36) + (s & 31);
            f1p[e0][idx] = v.x; f1p[e0 + 1][idx] = v.y;
            f1p[e0 + 2][idx] = v.z; f1p[e0 + 3][idx] = v.w;
        } else {
            f2s[e0][s] = v.x; f2s[e0 + 1][s] = v.y;
            f2s[e0 + 2][s] = v.z; f2s[e0 + 3][s] = v.w;
        }
    }
    __syncthreads();

    if (wv < 8) {
        // ---- waves 0-7: per-ei inclusive scans of f2 and t*f2 ----
        const int e = wv;
        float c0 = 0.0f, c1 = 0.0f;
        if (lane == 0) { P0[e][0] = 0.0f; P1[e][0] = 0.0f; }
        #pragma unroll
        for (int ch = 0; ch < 4; ++ch) {
            const int t = ch * 64 + lane;
            float v0 = f2s[e][t];
            float v1 = (float)t * v0;
            #pragma unroll
            for (int off = 1; off < 64; off <<= 1) {
                const float u0 = __shfl_up(v0, off, 64);
                const float u1 = __shfl_up(v1, off, 64);
                if (lane >= off) { v0 += u0; v1 += u1; }
            }
            P0[e][t + 1] = v0 + c0;
            P1[e][t + 1] = v1 + c1;
            c0 += __shfl(v0, 63, 64);
            c1 += __shfl(v1, 63, 64);
        }
    } else {
        // ---- waves 8-15: build G table for e = wv-8 ----
        const int e    = wv - 8;
        const int node = lane >> 2;
        const int p    = lane & 3;
        const float ck = (-CRANGE + (float)node * HSTEP) * LOG2E;
        float acc = 0.0f;
        #pragma unroll
        for (int blk = 0; blk < 2; ++blk) {
            const float4* fp = (const float4*)&f1p[e][(2 * p + blk) * 36];
            #pragma unroll
            for (int i4 = 0; i4 < 8; i4 += 2) {
                const float4 A = fp[i4];
                const float4 B = fp[i4 + 1];
                const float e0 = __builtin_amdgcn_exp2f(fminf(A.x * ck, 14.5f));
                const float e1 = __builtin_amdgcn_exp2f(fminf(A.y * ck, 14.5f));
                const float e2 = __builtin_amdgcn_exp2f(fminf(A.z * ck, 14.5f));
                const float e3 = __builtin_amdgcn_exp2f(fminf(A.w * ck, 14.5f));
                const float e4 = __builtin_amdgcn_exp2f(fminf(B.x * ck, 14.5f));
                const float e5 = __builtin_amdgcn_exp2f(fminf(B.y * ck, 14.5f));
                const float e6 = __builtin_amdgcn_exp2f(fminf(B.z * ck, 14.5f));
                const float e7 = __builtin_amdgcn_exp2f(fminf(B.w * ck, 14.5f));
                const float p01 = (1.0f + e0) * (1.0f + e1);
                const float p23 = (1.0f + e2) * (1.0f + e3);
                const float p45 = (1.0f + e4) * (1.0f + e5);
                const float p67 = (1.0f + e6) * (1.0f + e7);
                acc += __builtin_amdgcn_logf((p01 * p23) * (p45 * p67));
            }
        }
        acc += __shfl_xor(acc, 1, 64);
        acc += __shfl_xor(acc, 2, 64);
        if (p == 0) table[e][node] = acc * LN2;
    }
    __syncthreads();

    // ---- eval: e = tid>>7, t in {tb, tb+128} ----
    const int e  = tid >> 7;
    const int tb = tid & 127;
    float val = 0.0f;
    #pragma unroll
    for (int r = 0; r < 2; ++r) {
        const int t = tb + (r << 7);
        const float c = f2s[e][t];

        const float u = (c + CRANGE) * USCALE;
        int j = (int)floorf(u);
        j = (j < 1) ? 1 : ((j > NODES - 3) ? (NODES - 3) : j);
        const float tt  = u - (float)j;
        const float tm1 = tt - 1.0f;
        const float tm2 = tt - 2.0f;
        const float tp1 = tt + 1.0f;
        const float w_m1 = -tt * tm1 * tm2 * (1.0f / 6.0f);
        const float w_0  = tp1 * tm1 * tm2 * 0.5f;
        const float w_p1 = -tt * tp1 * tm2 * 0.5f;
        const float w_p2 = tt * tp1 * tm1 * (1.0f / 6.0f);
        const float Gc = table[e][j - 1] * w_m1 + table[e][j] * w_0
                       + table[e][j + 1] * w_p1 + table[e][j + 2] * w_p2;

        const int s  = t;
        const int t0 = (s - 20 > 0) ? (s - 20) : 0;
        const int t1 = (s + 20 < SIDE) ? (s + 20) : SIDE;
        const float a = f1p[e][((s >> 5) * 36) + (s & 31)];
        const float P0t0 = P0[e][t0], P0s = P0[e][s], P0t1 = P0[e][t1];
        const float P1t0 = P1[e][t0], P1s = P1[e][s], P1t1 = P1[e][t1];
        const float sf = (float)s;
        const float left  = (1.05f - 0.05f * sf) * (P0s - P0t0) + 0.05f * (P1s - P1t0);
        const float right = (1.0f + 0.05f * sf) * (P0t1 - P0s) - 0.05f * (P1t1 - P1s);
        val += Gc - a * (left + right);
    }

    // ---- block reduction (16 waves) ----
    for (int off = 32; off > 0; off >>= 1) val += __shfl_down(val, off, 64);
    if (lane == 0) wsum[wv] = val;
    __syncthreads();

    // ---- publish partial, drain, then take ticket (ticket reset to 0 by
    //      the preceding memset node, so winner == true last arrival) ----
    if (tid == 0) {
        float b = 0.0f;
        #pragma unroll
        for (int i = 0; i < 16; ++i) b += wsum[i];
        atomicExch(&partial[g], b);                       // device-scope write
        asm volatile("s_waitcnt vmcnt(0)" ::: "memory");  // exch globally complete
        s_tk = atomicAdd(ticket, 1u);                     // strictly after
    }
    __syncthreads();
    if (s_tk != (NBLK - 1)) return;

    // ---- winner (256th arrival): device-scope atomic reads of all partials ----
    float v = 0.0f;
    if (tid < NBLK) v = atomicAdd(&partial[tid], 0.0f);
    for (int off = 32; off > 0; off >>= 1) v += __shfl_down(v, off, 64);
    if (lane == 0) wsum[wv] = v;
    __syncthreads();
    if (tid == 0) {
        const float total = (wsum[0] + wsum[1]) + (wsum[2] + wsum[3]);
        out[0] = total * (1.0f / 65536.0f);
    }
}

extern "C" void kernel_launch(void* const* d_in, const int* in_sizes, int n_in,
                              void* d_out, int out_size, void* d_ws, size_t ws_size,
                              hipStream_t stream) {
    const float* emb = (const float*)d_in[0];   // (64,256,64) f32
    float* partial = (float*)d_ws;              // 256 floats
    unsigned int* ticket = (unsigned int*)((char*)d_ws + NBLK * sizeof(float));
    float* out = (float*)d_out;                 // 1 float

    hipMemsetAsync(ticket, 0, sizeof(unsigned int), stream);  // graph memset node
    sigloss_fused<<<NBLK, 1024, 0, stream>>>(emb, partial, ticket, out);
}

// Round 17
// 11.538 us; speedup vs baseline: 1.5902x; 1.5902x over previous
//
#include <hip/hip_runtime.h>

// SigmoidLoss: out = sum_n mean_{s,t} [ softplus(z) - W[s,t]*z ],  z = f1[n,s]*f2[n,t]
// f1[n,s] = emb[bi, s, ei], f2[n,s] = emb[32+bi, s, ei],  n = bi*64 + ei
// W banded: W[s,t] = 1-0.05q, q = (t>=s ? t-s : s-t-1), zero for q >= 20.
//
// G-table: G_e(c) = sum_s softplus(f1[s]*c) at 16 nodes on [-6,6]; 4-point
// cubic Lagrange eval (absmax 0.0 across R11-R13). Exact softplus in build:
// ln2*log2(1+exp2(x)), x clamped <= 14.5; ONE v_log_f32 per 8 elems.
// W-term via per-ei prefix sums P0 = sum f2, P1 = sum t*f2 (closed-form band).
//
// R17 = R12 restored (empirical optimum, 11.5 us). Fusion variants (R4/R16)
// and bigger blocks (R13) all regressed or were null; two graph nodes with a
// 64-thread reduce is the floor on this harness.
//
// Block = (bi, 4 consecutive ei), 512 blocks x 512 threads. Staging is one
// float4 per thread. Waves 0-3 scan f2 (per-ei) CONCURRENTLY with waves 4-7
// building the 4 G-tables. XCD swizzle keeps line-sharing blocks on one XCD.

#define SIDE 256
#define NB 32
#define NE 64
#define NBLK 512          // 32 bi x 16 ei-groups
#define LOG2E 1.4426950408889634f
#define LN2 0.6931471805599453f
#define NODES 16
#define CRANGE 6.0f
#define HSTEP (12.0f / 15.0f)
#define USCALE (15.0f / 12.0f)

__global__ __launch_bounds__(512) void sigloss_main(const float* __restrict__ emb,
                                                    float* __restrict__ partial) {
    const int bid  = blockIdx.x;
    const int g    = (bid >> 3) + ((bid & 7) << 6);  // XCD swizzle (bijective on 512)
    const int bi   = g >> 4;
    const int ei0  = (g & 15) << 2;
    const int tid  = threadIdx.x;   // 0..511
    const int wv   = tid >> 6;      // wave 0..7
    const int lane = tid & 63;

    // f1 part-padded: 8 blocks of 32 s, stride 36 (16B-aligned, distinct banks)
    __shared__ __align__(16) float f1p[4][8 * 36];
    __shared__ float f2s[4][SIDE + 4];
    __shared__ float P0[4][SIDE + 1];
    __shared__ float P1[4][SIDE + 1];
    __shared__ float table[4][NODES + 2];
    __shared__ float wsum[8];

    // ---- staging: one float4 (4 ei) per thread ----
    {
        const int half = tid >> 8;          // 0: f1, 1: f2
        const int s    = tid & 255;
        const float4 v = *(const float4*)(emb
            + (size_t)(half ? NB + bi : bi) * (SIDE * NE) + (size_t)s * NE + ei0);
        if (half == 0) {
            const int idx = ((s >> 5) * 36) + (s & 31);
            f1p[0][idx] = v.x; f1p[1][idx] = v.y; f1p[2][idx] = v.z; f1p[3][idx] = v.w;
        } else {
            f2s[0][s] = v.x; f2s[1][s] = v.y; f2s[2][s] = v.z; f2s[3][s] = v.w;
        }
    }
    __syncthreads();

    if (wv < 4) {
        // ---- waves 0-3: per-ei inclusive scans of f2 and t*f2 ----
        const int e = wv;
        float c0 = 0.0f, c1 = 0.0f;
        if (lane == 0) { P0[e][0] = 0.0f; P1[e][0] = 0.0f; }
        #pragma unroll
        for (int ch = 0; ch < 4; ++ch) {
            const int t = ch * 64 + lane;
            float v0 = f2s[e][t];
            float v1 = (float)t * v0;
            #pragma unroll
            for (int off = 1; off < 64; off <<= 1) {
                const float u0 = __shfl_up(v0, off, 64);
                const float u1 = __shfl_up(v1, off, 64);
                if (lane >= off) { v0 += u0; v1 += u1; }
            }
            P0[e][t + 1] = v0 + c0;
            P1[e][t + 1] = v1 + c1;
            c0 += __shfl(v0, 63, 64);
            c1 += __shfl(v1, 63, 64);
        }
    } else {
        // ---- waves 4-7: build G table for e = wv-4 ----
        // node = lane>>2 (16 nodes), part = lane&3 (4 parts x 64 s)
        const int e    = wv - 4;
        const int node = lane >> 2;
        const int p    = lane & 3;
        const float ck = (-CRANGE + (float)node * HSTEP) * LOG2E;
        float acc = 0.0f;
        #pragma unroll
        for (int blk = 0; blk < 2; ++blk) {
            const float4* fp = (const float4*)&f1p[e][(2 * p + blk) * 36];
            #pragma unroll
            for (int i4 = 0; i4 < 8; i4 += 2) {
                const float4 A = fp[i4];
                const float4 B = fp[i4 + 1];
                const float e0 = __builtin_amdgcn_exp2f(fminf(A.x * ck, 14.5f));
                const float e1 = __builtin_amdgcn_exp2f(fminf(A.y * ck, 14.5f));
                const float e2 = __builtin_amdgcn_exp2f(fminf(A.z * ck, 14.5f));
                const float e3 = __builtin_amdgcn_exp2f(fminf(A.w * ck, 14.5f));
                const float e4 = __builtin_amdgcn_exp2f(fminf(B.x * ck, 14.5f));
                const float e5 = __builtin_amdgcn_exp2f(fminf(B.y * ck, 14.5f));
                const float e6 = __builtin_amdgcn_exp2f(fminf(B.z * ck, 14.5f));
                const float e7 = __builtin_amdgcn_exp2f(fminf(B.w * ck, 14.5f));
                const float p01 = (1.0f + e0) * (1.0f + e1);
                const float p23 = (1.0f + e2) * (1.0f + e3);
                const float p45 = (1.0f + e4) * (1.0f + e5);
                const float p67 = (1.0f + e6) * (1.0f + e7);
                acc += __builtin_amdgcn_logf((p01 * p23) * (p45 * p67));
            }
        }
        acc += __shfl_xor(acc, 1, 64);
        acc += __shfl_xor(acc, 2, 64);
        if (p == 0) table[e][node] = acc * LN2;
    }
    __syncthreads();

    // ---- eval: e = tid>>7, t in {tb, tb+128} ----
    const int e  = tid >> 7;
    const int tb = tid & 127;
    float val = 0.0f;
    #pragma unroll
    for (int r = 0; r < 2; ++r) {
        const int t = tb + (r << 7);
        const float c = f2s[e][t];

        // cubic interpolation of G_e at c
        const float u = (c + CRANGE) * USCALE;
        int j = (int)floorf(u);
        j = (j < 1) ? 1 : ((j > NODES - 3) ? (NODES - 3) : j);
        const float tt  = u - (float)j;
        const float tm1 = tt - 1.0f;
        const float tm2 = tt - 2.0f;
        const float tp1 = tt + 1.0f;
        const float w_m1 = -tt * tm1 * tm2 * (1.0f / 6.0f);
        const float w_0  = tp1 * tm1 * tm2 * 0.5f;
        const float w_p1 = -tt * tp1 * tm2 * 0.5f;
        const float w_p2 = tt * tp1 * tm1 * (1.0f / 6.0f);
        const float Gc = table[e][j - 1] * w_m1 + table[e][j] * w_0
                       + table[e][j + 1] * w_p1 + table[e][j + 2] * w_p2;

        // W-term for row s = t
        const int s  = t;
        const int t0 = (s - 20 > 0) ? (s - 20) : 0;
        const int t1 = (s + 20 < SIDE) ? (s + 20) : SIDE;
        const float a = f1p[e][((s >> 5) * 36) + (s & 31)];
        const float P0t0 = P0[e][t0], P0s = P0[e][s], P0t1 = P0[e][t1];
        const float P1t0 = P1[e][t0], P1s = P1[e][s], P1t1 = P1[e][t1];
        const float sf = (float)s;
        const float left  = (1.05f - 0.05f * sf) * (P0s - P0t0) + 0.05f * (P1s - P1t0);
        const float right = (1.0f + 0.05f * sf) * (P0t1 - P0s) - 0.05f * (P1t1 - P1s);
        val += Gc - a * (left + right);
    }

    // ---- block reduction (8 waves) ----
    for (int off = 32; off > 0; off >>= 1) val += __shfl_down(val, off, 64);
    if (lane == 0) wsum[wv] = val;
    __syncthreads();
    if (tid == 0) {
        float b0 = (wsum[0] + wsum[1]) + (wsum[2] + wsum[3]);
        float b1 = (wsum[4] + wsum[5]) + (wsum[6] + wsum[7]);
        partial[bid] = b0 + b1;
    }
}

__global__ __launch_bounds__(64) void sigloss_reduce(const float* __restrict__ partial,
                                                     float* __restrict__ out) {
    const int lane = threadIdx.x;  // one wave
    const float4* p4 = (const float4*)partial;   // 128 float4
    const float4 q0 = p4[lane];
    const float4 q1 = p4[lane + 64];
    float v = ((q0.x + q0.y) + (q0.z + q0.w)) + ((q1.x + q1.y) + (q1.z + q1.w));
    for (int off = 32; off > 0; off >>= 1) v += __shfl_down(v, off, 64);
    if (lane == 0) out[0] = v * (1.0f / 65536.0f);
}

extern "C" void kernel_launch(void* const* d_in, const int* in_sizes, int n_in,
                              void* d_out, int out_size, void* d_ws, size_t ws_size,
                              hipStream_t stream) {
    const float* emb = (const float*)d_in[0];   // (64,256,64) f32
    float* partial = (float*)d_ws;              // 512 floats scratch
    float* out = (float*)d_out;                 // 1 float
    sigloss_main<<<NBLK, 512, 0, stream>>>(emb, partial);
    sigloss_reduce<<<1, 64, 0, stream>>>(partial, out);
}